// Round 1
// baseline (286.666 us; speedup 1.0000x reference)
//
#include <hip/hip_runtime.h>
#include <hip/hip_bf16.h>
#include <math.h>

#define IN_DIM 512
#define HID    1024
#define NE     16
#define T_TOK  8192
#define NPAIR  (T_TOK*2)

typedef __attribute__((ext_vector_type(8))) short bf16x8;
typedef __attribute__((ext_vector_type(4))) float f32x4;

__device__ __forceinline__ unsigned short f2b(float f){
  unsigned u = __float_as_uint(f);
  u += 0x7FFF + ((u >> 16) & 1);           // round-to-nearest-even
  return (unsigned short)(u >> 16);
}
__device__ __forceinline__ float b2f(unsigned short u){
  return __uint_as_float(((unsigned)u) << 16);
}

// Barrier WITHOUT the vmcnt(0) drain __syncthreads() forces.
__device__ __forceinline__ void barrier_lds_only(){
  asm volatile("s_waitcnt lgkmcnt(0)" ::: "memory");
  __builtin_amdgcn_s_barrier();
}

// global -> LDS direct DMA, 16 B per lane. LDS dest is wave-uniform base + lane*16.
typedef const __attribute__((address_space(1))) unsigned int* gas1_t;
typedef __attribute__((address_space(3))) unsigned int* las3_t;
__device__ __forceinline__ void gl16(const unsigned short* g, unsigned short* l){
  __builtin_amdgcn_global_load_lds((gas1_t)(const void*)g, (las3_t)(void*)l, 16, 0, 0);
}

// ---------------- prep: batched transpose+convert, W1 and W2 fused in one launch ----
// blocks [0,8192):  W1 [E][512][1024]  -> w1t [E][1024][512] bf16
// blocks [8192,16384): W2 [E][1024][512] -> w2t [E][512][1024] bf16
__global__ __launch_bounds__(256) void tconv2_kernel(const float* __restrict__ A1,
                                                     unsigned short* __restrict__ O1,
                                                     const float* __restrict__ A2,
                                                     unsigned short* __restrict__ O2){
  __shared__ float tile[32][33];
  int b = blockIdx.x;
  const float* src; unsigned short* dst; int M, N, m0, n0;
  if (b < 8192){
    M = IN_DIM; N = HID;
    int e = b >> 9, r = b & 511;              // 32 x 16 tiles per expert
    n0 = (r & 31)*32; m0 = (r >> 5)*32;
    src = A1 + (size_t)e*M*N; dst = O1 + (size_t)e*M*N;
  } else {
    int b2 = b - 8192;
    M = HID; N = IN_DIM;
    int e = b2 >> 9, r = b2 & 511;            // 16 x 32 tiles per expert
    n0 = (r & 15)*32; m0 = (r >> 4)*32;
    src = A2 + (size_t)e*M*N; dst = O2 + (size_t)e*M*N;
  }
  int c = threadIdx.x & 31, r = threadIdx.x >> 5;
  #pragma unroll
  for (int i=0;i<4;i++)
    tile[r + i*8][c] = src[(size_t)(m0 + r + i*8)*N + n0 + c];
  __syncthreads();
  int tr  = threadIdx.x >> 3;
  int tc4 = (threadIdx.x & 7) * 4;
  ushort4 o;
  o.x = f2b(tile[tc4+0][tr]); o.y = f2b(tile[tc4+1][tr]);
  o.z = f2b(tile[tc4+2][tr]); o.w = f2b(tile[tc4+3][tr]);
  *(ushort4*)(&dst[(size_t)(n0 + tr)*M + m0 + tc4]) = o;
}

// ---------------- router: one wave per token; NO global atomics ----------------
__global__ __launch_bounds__(256) void router_kernel(
    const float* __restrict__ x, const float* __restrict__ Wr, const float* __restrict__ br,
    unsigned short* __restrict__ xb, int* __restrict__ eid, float* __restrict__ pw)
{
  int wid = threadIdx.x >> 6, lane = threadIdx.x & 63;
  int t = blockIdx.x*4 + wid;
  const float4* xr4 = (const float4*)(x + (size_t)t*IN_DIM);
  ushort4*      xb4 = (ushort4*)(xb + (size_t)t*IN_DIM);

  float acc[NE];
  #pragma unroll
  for (int i=0;i<NE;i++) acc[i]=0.f;

  #pragma unroll
  for (int j=0;j<2;j++){
    int f = j*64 + lane;
    float4 v = xr4[f];
    ushort4 o; o.x=f2b(v.x); o.y=f2b(v.y); o.z=f2b(v.z); o.w=f2b(v.w);
    xb4[f] = o;
    const float4* wr4 = (const float4*)(Wr + (size_t)(f*4)*NE);
    const float* vv = (const float*)&v;
    #pragma unroll
    for (int rr=0; rr<4; rr++){
      float xv = vv[rr];
      #pragma unroll
      for (int q=0;q<4;q++){
        float4 w = wr4[rr*4+q];
        acc[q*4+0] += xv*w.x; acc[q*4+1] += xv*w.y;
        acc[q*4+2] += xv*w.z; acc[q*4+3] += xv*w.w;
      }
    }
  }
  #pragma unroll
  for (int off=32; off>=1; off>>=1){
    #pragma unroll
    for (int i=0;i<NE;i++) acc[i] += __shfl_xor(acc[i], off, 64);
  }
  if (lane==0){
    #pragma unroll
    for (int i=0;i<NE;i++) acc[i] += br[i];
    int e0=0; float l0=acc[0];
    #pragma unroll
    for (int i=1;i<NE;i++) if (acc[i] > l0){ l0=acc[i]; e0=i; }
    int e1=-1; float l1=-3.0e38f;
    #pragma unroll
    for (int i=0;i<NE;i++) if (i!=e0 && acc[i] > l1){ l1=acc[i]; e1=i; }
    float w0 = 1.f/(1.f + __expf(l1 - l0));
    float w1 = 1.f - w0;
    pw[t*2+0] = w0; pw[t*2+1] = w1;
    eid[t*2+0] = e0; eid[t*2+1] = e1;
  }
}

// ---------------- bucket build: 16 blocks (one per expert), ballot-compact ----------
__global__ __launch_bounds__(1024) void bucket_kernel(const int* __restrict__ eid,
                                                      int* __restrict__ cnt,
                                                      int* __restrict__ bucket){
  int e = blockIdx.x;
  __shared__ int lbase;
  if (threadIdx.x == 0) lbase = 0;
  __syncthreads();
  int lane = threadIdx.x & 63, wid = threadIdx.x >> 6;
  int* be = bucket + e*T_TOK;
  for (int c = wid*64; c < NPAIR; c += 1024){
    int p = c + lane;
    bool ok = (eid[p] == e);
    unsigned long long m = __ballot(ok);
    int rank = __popcll(m & ((1ull << lane) - 1ull));
    int count = __popcll(m);
    int base = 0;
    if (lane == 0) base = atomicAdd(&lbase, count);
    base = __shfl(base, 0, 64);
    if (ok) be[base + rank] = p;
  }
  __syncthreads();
  if (threadIdx.x == 0) cnt[e] = lbase;
}

// ---------------- PERSISTENT grouped GEMM, R10: 128x128 tile, global_load_lds ------
// m97-structure port: 4 waves, 64x64 output/wave (acc[4][4]), BK=32 double-buffered,
// width-16 global_load_lds staging (4 instr/thread/K-step), counted vmcnt(4) so the
// next tile's loads stay in flight across both barriers (drain only at tile end).
// XOR swizzle preserved by PRE-SWIZZLING the per-lane GLOBAL source chunk (m173):
// LDS dest stays linear base+lane*16 (matches [row][chunk] since row=tid>>2,chunk=tid&3),
// LDS[row][q] holds global chunk q^((row>>1)&3); fragment reads use the same XOR.
// FIRST: A = xb gathered by token; hb[ebase+pos][n] = gelu(A@W1t^T + b1)
// !FIRST: A = hb sequential; opb[pair][n] = bf16(pw[pair]*(A@W2t^T + b2)) (no atomics)

#define STAGE(buf, kt) do{ \
      gl16(Ag0 + (kt)*32, ldsA + (buf)*4096); \
      gl16(Ag1 + (kt)*32, ldsA + (buf)*4096 + 2048); \
      gl16(Bg0 + (kt)*32, ldsB + (buf)*4096); \
      gl16(Bg1 + (kt)*32, ldsB + (buf)*4096 + 2048); \
    }while(0)

#define COMPUTE(buf) do{ \
      const unsigned short* Ac = lds + (buf)*4096; \
      const unsigned short* Bc = lds + 8192 + (buf)*4096; \
      bf16x8 af[4], bfr[4]; \
      _Pragma("unroll") \
      for (int s=0;s<4;s++) af[s]  = *(const bf16x8*)(Ac + (wm + s*16 + fr)*32 + pf8); \
      _Pragma("unroll") \
      for (int u=0;u<4;u++) bfr[u] = *(const bf16x8*)(Bc + (wn + u*16 + fr)*32 + pf8); \
      _Pragma("unroll") \
      for (int s=0;s<4;s++) \
        _Pragma("unroll") \
        for (int u=0;u<4;u++) \
          acc[s][u] = __builtin_amdgcn_mfma_f32_16x16x32_bf16(af[s], bfr[u], acc[s][u], 0,0,0); \
    }while(0)

#define KBODY(k, P) do{ \
      STAGE((P)^1, (k)+1); \
      asm volatile("s_waitcnt vmcnt(4)" ::: "memory"); \
      barrier_lds_only(); \
      COMPUTE(P); \
      barrier_lds_only(); \
    }while(0)

template<int KDIM, int NDIM, bool FIRST>
__global__ __launch_bounds__(256) void moe_gemm(
    const unsigned short* __restrict__ A,
    const unsigned short* __restrict__ Bm,    // [E][NDIM][KDIM] bf16 (pre-transposed)
    const float* __restrict__ bias,           // [E][NDIM]
    const int* __restrict__ cnt,
    const int* __restrict__ bucket,
    const float* __restrict__ pw,
    unsigned short* __restrict__ hb,          // FIRST: out (bucket-order) / !FIRST: in
    unsigned short* __restrict__ opb)         // !FIRST: out (pair rows)
{
  constexpr int NS  = KDIM / 32;              // K-steps per tile (16 or 32, both even)
  constexpr int NBT = NDIM / 128;             // n-tiles per expert

  int ntiles = 0;
  #pragma unroll
  for (int j=0;j<NE;j++) ntiles += ((cnt[j]+127)>>7)*NBT;

  // A[2][128][32] bf16 @ shorts 0, B[2][128][32] @ shorts 8192  -> 32 KB total
  __shared__ unsigned short lds[16384];

  const int tid  = threadIdx.x;
  const int lane = tid & 63, wid = tid >> 6;
  const int lr = tid >> 2;                    // staging row (lo half), 0..63
  const int c  = tid & 3;                     // staging chunk position
  const int cs = (c ^ ((lr >> 1) & 3)) * 8;   // PRE-SWIZZLED global source chunk
  unsigned short* ldsA = lds + wid*512;       // wave-uniform DMA bases (+buf*4096, hi +2048)
  unsigned short* ldsB = lds + 8192 + wid*512;

  const int wm = (wid>>1)*64, wn = (wid&1)*64;
  const int fr = lane & 15, fb = lane >> 4;
  const int pf8 = (fb ^ ((fr >> 1) & 3)) * 8; // matches source-side swizzle
  const int fq = fb*4;

  for (int t = blockIdx.x; t < ntiles; t += gridDim.x){
    // ---- tile -> (e, tloc, ebase, ce, itl) via register scan (no arrays) ----
    int e=0, tloc=0, ebase=0, ce=0, itl=1;
    {
      int cum=0, crow=0;
      #pragma unroll
      for (int j=0;j<NE;j++){
        int cj = cnt[j];
        int it = (cj+127)>>7;
        int tj = it * NBT;
        bool in = (t >= cum) & (t < cum+tj);
        if (in){ e=j; tloc=t-cum; ebase=crow; ce=cj; itl=it; }
        cum += tj; crow += cj;
      }
    }
    const int i0 = (tloc % itl) * 128;        // i0-fastest ordering (B reuse in L2)
    const int n0 = (tloc / itl) * 128;

    const int* buck = bucket + e*T_TOK;
    int arow0, arow1;
    if (FIRST){
      int p0 = i0 + lr, p1 = i0 + 64 + lr;
      arow0 = buck[(p0 < ce) ? p0 : i0] >> 1;
      arow1 = buck[(p1 < ce) ? p1 : i0] >> 1;
    } else {
      arow0 = ebase + i0 + lr;      if (arow0 > NPAIR-1) arow0 = NPAIR-1;
      arow1 = ebase + i0 + 64 + lr; if (arow1 > NPAIR-1) arow1 = NPAIR-1;
    }
    const unsigned short* Ag0 = A + (size_t)arow0*KDIM + cs;
    const unsigned short* Ag1 = A + (size_t)arow1*KDIM + cs;
    const unsigned short* Bg0 = Bm + (size_t)e*NDIM*KDIM + (size_t)(n0 + lr)*KDIM + cs;
    const unsigned short* Bg1 = Bg0 + (size_t)64*KDIM;

    f32x4 acc[4][4];
    #pragma unroll
    for (int s=0;s<4;s++)
      #pragma unroll
      for (int u=0;u<4;u++)
        #pragma unroll
        for (int j=0;j<4;j++) acc[s][u][j] = 0.f;

    // ---- K loop: tile k in buf k&1; stage k+1 while computing k; vmcnt never 0 ----
    STAGE(0, 0);
    for (int k=0; k+1 < NS-1; k+=2){ KBODY(k, 0); KBODY(k+1, 1); }
    KBODY(NS-2, 0);                           // NS even -> leftover body has parity 0
    asm volatile("s_waitcnt vmcnt(0)" ::: "memory");
    barrier_lds_only();
    COMPUTE(1);                               // last tile (NS-1)&1 == 1
    barrier_lds_only();                       // seal buf1 reads before next tile's STAGE(1,1)

    // ---- epilogue: C/D layout col=lane&15, row=(lane>>4)*4+reg [m89-verified] ----
    #pragma unroll
    for (int s=0;s<4;s++){
      #pragma unroll
      for (int i=0;i<4;i++){
        int row = wm + s*16 + fq + i;
        int pos = i0 + row;
        if (pos >= ce) continue;
        #pragma unroll
        for (int u=0;u<4;u++){
          int n = n0 + wn + u*16 + fr;
          float v = acc[s][u][i] + bias[e*NDIM + n];
          if (FIRST){
            float g = 0.5f*v*(1.f + erff(v*0.70710678118654752f));   // exact GELU
            hb[(size_t)(ebase + pos)*NDIM + n] = f2b(g);
          } else {
            int pair = buck[pos];
            opb[(size_t)pair*NDIM + n] = f2b(pw[pair]*v);
          }
        }
      }
    }
  }
}

#undef KBODY
#undef COMPUTE
#undef STAGE

// ---------------- combine: out = x + opb[2t] + opb[2t+1] (coalesced) ----------------
__global__ __launch_bounds__(256) void combine_kernel(const float* __restrict__ x,
                                                      const unsigned short* __restrict__ opb,
                                                      float* __restrict__ out){
  int i = blockIdx.x*256 + threadIdx.x;
  int t  = i >> 7;
  int c4 = i & 127;
  float4 v = ((const float4*)x)[i];
  ushort4 a = ((const ushort4*)opb)[(size_t)(2*t)*128 + c4];
  ushort4 b = ((const ushort4*)opb)[(size_t)(2*t+1)*128 + c4];
  v.x += b2f(a.x) + b2f(b.x);
  v.y += b2f(a.y) + b2f(b.y);
  v.z += b2f(a.z) + b2f(b.z);
  v.w += b2f(a.w) + b2f(b.w);
  ((float4*)out)[i] = v;
}

// ---------------- launch ----------------
extern "C" void kernel_launch(void* const* d_in, const int* in_sizes, int n_in,
                              void* d_out, int out_size, void* d_ws, size_t ws_size,
                              hipStream_t stream)
{
  const float* x  = (const float*)d_in[0];
  const float* Wr = (const float*)d_in[1];
  const float* br = (const float*)d_in[2];
  const float* W1 = (const float*)d_in[3];
  const float* b1 = (const float*)d_in[4];
  const float* W2 = (const float*)d_in[5];
  const float* b2 = (const float*)d_in[6];
  float* out = (float*)d_out;
  char* ws = (char*)d_ws;

  // ws layout (bytes) — identical footprint to the passing layout
  int*            cnt    = (int*)(ws + 0);            // 64 B
  int*            bucket = (int*)(ws + 1024);         // 16*8192*4 = 524288
  float*          pw     = (float*)(ws + 525312);     // 16384*4   = 65536
  unsigned short* xb     = (unsigned short*)(ws + 590848);    // 8192*512*2  = 8388608
  unsigned short* w1t    = (unsigned short*)(ws + 8979456);   // 16*512*1024*2 = 16777216
  unsigned short* w2t    = (unsigned short*)(ws + 25756672);  // 16777216
  unsigned short* hb     = (unsigned short*)(ws + 42533888);  // 16384*1024*2 = 33554432
  // aliases (stream-ordered lifetimes):
  //  eid at hb head: router writes, bucket reads, dead before GEMM1 writes hb
  //  opb in w1t region: w1t dead after GEMM1; opb = GEMM2 out, read by combine
  int*            eid    = (int*)(ws + 42533888);     // 16384*4 = 65536
  unsigned short* opb    = w1t;                       // 16384*512*2 = 16777216 (exact fit)

  router_kernel<<<T_TOK/4, 256, 0, stream>>>(x, Wr, br, xb, eid, pw);
  bucket_kernel<<<NE, 1024, 0, stream>>>(eid, cnt, bucket);
  tconv2_kernel<<<16384, 256, 0, stream>>>(W1, w1t, W2, w2t);
  moe_gemm<IN_DIM, HID, true ><<<1024, 256, 0, stream>>>(
      xb, w1t, b1, cnt, bucket, pw, hb, opb);
  moe_gemm<HID, IN_DIM, false><<<1024, 256, 0, stream>>>(
      hb, w2t, b2, cnt, bucket, pw, hb, opb);
  combine_kernel<<<(T_TOK*IN_DIM/4)/256, 256, 0, stream>>>(x, opb, out);
}